// Round 24
// baseline (155.339 us; speedup 1.0000x reference)
//
#include <hip/hip_runtime.h>
#include <hip/hip_bf16.h>
#include <stdint.h>

#define B_ 4
#define T_ 2048
#define C_ 1024
#define H_ 16
#define D_ 64
#define BH_ (B_*H_)
#define M_ (B_*T_)   // 8192 rows

typedef __attribute__((ext_vector_type(8))) short short8;
typedef __attribute__((ext_vector_type(4))) float f32x4;
typedef __attribute__((ext_vector_type(16))) float f32x16;

#if __has_builtin(__builtin_amdgcn_exp2f)
#define EXP2(x) __builtin_amdgcn_exp2f(x)
#else
#define EXP2(x) exp2f(x)
#endif

// 1/sqrt(D) * log2(e), folded into Q at QKV-GEMM epilogue
#define QSCALE 0.18033688011112043f

__device__ __forceinline__ unsigned short f2bf(float f) {
  union { float f; unsigned int u; } v; v.f = f;
  unsigned int r = v.u + 0x7FFFu + ((v.u >> 16) & 1u);   // RNE
  return (unsigned short)(r >> 16);
}

__device__ __forceinline__ unsigned int cvtpk_bf16(float lo, float hi) {
  unsigned int r;
  asm("v_cvt_pk_bf16_f32 %0, %1, %2" : "=v"(r) : "v"(lo), "v"(hi));
  return r;
}

__device__ __forceinline__ void gload_lds16(const void* g, void* l) {
  __builtin_amdgcn_global_load_lds(
      (__attribute__((address_space(1))) void*)g,
      (__attribute__((address_space(3))) void*)l, 16, 0, 0);
}

// ---------------- fp32 -> bf16 convert (vectorized) ----------------
__global__ __launch_bounds__(256) void k_cvt(const float* __restrict__ in,
                                             unsigned short* __restrict__ out, int n) {
  int i = (blockIdx.x * 256 + threadIdx.x) * 4;
  if (i >= n) return;
  float4 v = *reinterpret_cast<const float4*>(in + i);
  union { unsigned short u[4]; unsigned long long ll; } o;
  o.u[0] = f2bf(v.x); o.u[1] = f2bf(v.y); o.u[2] = f2bf(v.z); o.u[3] = f2bf(v.w);
  *reinterpret_cast<unsigned long long*>(out + i) = o.ll;
}

// ---------------- transpose+convert W [K][N] f32 -> Wt [N][K] bf16 ----------------
__global__ __launch_bounds__(256) void k_tr(const float* __restrict__ W,
                                            unsigned short* __restrict__ Wt, int K, int N) {
  __shared__ float t[32][33];
  int n0 = blockIdx.x * 32, k0 = blockIdx.y * 32;
  int tx = threadIdx.x, ty = threadIdx.y;    // (32,8)
  #pragma unroll
  for (int j = 0; j < 4; j++)
    t[ty + j*8][tx] = W[(size_t)(k0 + ty + j*8) * N + n0 + tx];
  __syncthreads();
  #pragma unroll
  for (int j = 0; j < 4; j++)
    Wt[(size_t)(n0 + ty + j*8) * K + k0 + tx] = f2bf(t[tx][ty + j*8]);
}

// ---------------- GEMM v4.2: 128x128, BK=64, 2-tile-deep prefetch, counted vmcnt ---
// Round-24 delta: after all waves read tile t's fragments (extra s_barrier), stage
// t+2 into the CURRENT buffer; tile-end wait is vmcnt(8) — drains only t+1's loads
// (issued a full tile earlier, HBM latency fully covered) while t+2's 8 loads fly
// across the barrier. Never vmcnt(0) mid-loop (T4). Race note: pre-barrier ds_reads
// return in ~120cy; t+2 gload LDS-writes land >=200-900cy post-barrier.
template<int QKV>
__global__ __launch_bounds__(256) void k_gemm4(const unsigned short* __restrict__ A,
                                               const unsigned short* __restrict__ Bt,
                                               const float* __restrict__ bias,
                                               void* __restrict__ outp, int N, int K) {
  __shared__ __align__(16) unsigned short Al[2][128*64];   // 32 KB
  __shared__ __align__(16) unsigned short Bl[2][128*64];   // 32 KB

  const int tid = threadIdx.x;
  const int lane = tid & 63, wv = tid >> 6;
  const int lg = lane >> 4, lr = lane & 15;
  const int wm = wv >> 1, wn = wv & 1;     // 2M x 2N

  // T1: XCD-aware chunked remap (nwg % 8 == 0: 1536 / 512)
  const int nwg = gridDim.x * gridDim.y;
  const int l = blockIdx.y * gridDim.x + blockIdx.x;
  const int wg = (l & 7) * (nwg >> 3) + (l >> 3);
  const int m0 = (wg / gridDim.x) * 128;
  const int n0 = (wg % gridDim.x) * 128;

  const int NT = K >> 6;

  auto stageA = [&](int s, int t) {
    #pragma unroll
    for (int u = 0; u < 4; ++u) {
      int gi = tid + u*256;
      int row = gi >> 3, g = gi & 7;
      gload_lds16(A + (size_t)(m0 + row) * K + t*64 + (g ^ (row & 7)) * 8,
                  (char*)Al[s] + gi*16);
    }
  };
  auto stageB = [&](int s, int t) {
    #pragma unroll
    for (int u = 0; u < 4; ++u) {
      int gi = tid + u*256;
      int row = gi >> 3, g = gi & 7;
      gload_lds16(Bt + (size_t)(n0 + row) * K + t*64 + (g ^ (row & 7)) * 8,
                  (char*)Bl[s] + gi*16);
    }
  };

  f32x4 acc[4][4];
  #pragma unroll
  for (int i = 0; i < 4; ++i)
    #pragma unroll
    for (int j = 0; j < 4; ++j) acc[i][j] = (f32x4){0.f, 0.f, 0.f, 0.f};

  // prologue: tiles 0 and 1 staged; drain only tile 0 (vmcnt(8) keeps tile 1 flying)
  stageA(0, 0); stageB(0, 0);
  if (NT > 1) { stageA(1, 1); stageB(1, 1); }
  asm volatile("s_waitcnt vmcnt(8)" ::: "memory");
  __builtin_amdgcn_s_barrier();

  for (int t = 0; t < NT; ++t) {
    const char* Asb = (const char*)Al[t & 1];
    const char* Bsb = (const char*)Bl[t & 1];
    const bool sn2 = (t + 2 < NT);
    short8 af[4][2], bf[4][2];

    // read all A + B fragments of tile t (16 x ds_read_b128, swizzled)
    #pragma unroll
    for (int mf = 0; mf < 4; ++mf) {
      int row = wm*64 + mf*16 + lr; int r7 = row & 7;
      af[mf][0] = *(const short8*)(Asb + row*128 + ((lg      ^ r7) << 4));
      af[mf][1] = *(const short8*)(Asb + row*128 + (((4|lg) ^ r7) << 4));
    }
    #pragma unroll
    for (int nf = 0; nf < 4; ++nf) {
      int col = wn*64 + nf*16 + lr; int c7 = col & 7;
      bf[nf][0] = *(const short8*)(Bsb + col*128 + ((lg      ^ c7) << 4));
      bf[nf][1] = *(const short8*)(Bsb + col*128 + (((4|lg) ^ c7) << 4));
    }
    // all waves' reads of this buffer issued -> safe to prefetch t+2 into it
    __builtin_amdgcn_s_barrier();
    if (sn2) { stageA(t & 1, t + 2); stageB(t & 1, t + 2); }

    asm volatile("s_waitcnt lgkmcnt(0)" ::: "memory");
    __builtin_amdgcn_sched_barrier(0);
    __builtin_amdgcn_s_setprio(1);
    #pragma unroll
    for (int kh = 0; kh < 2; ++kh)
      #pragma unroll
      for (int mf = 0; mf < 4; ++mf)
        #pragma unroll
        for (int nf = 0; nf < 4; ++nf)
          acc[mf][nf] = __builtin_amdgcn_mfma_f32_16x16x32_bf16(
              af[mf][kh], bf[nf][kh], acc[mf][nf], 0, 0, 0);
    __builtin_amdgcn_s_setprio(0);

    if (sn2) asm volatile("s_waitcnt vmcnt(8)" ::: "memory");  // drain t+1 only
    else     asm volatile("s_waitcnt vmcnt(0)" ::: "memory");
    __builtin_amdgcn_s_barrier();
  }

  if (QKV) {
    unsigned short* qb = (unsigned short*)outp;
    const size_t SZ = (size_t)BH_ * T_ * D_;
    #pragma unroll
    for (int i4 = 0; i4 < 4; ++i4) {
      int mb = m0 + wm*64 + i4*16 + lg*4;
      #pragma unroll
      for (int nf = 0; nf < 4; ++nf) {
        int n = n0 + wn*64 + nf*16 + lr;
        float bv = bias[n];
        int which = n >> 10, c = n & 1023, h = c >> 6, d = c & 63;
        if (which == 2) {
          // V: transposed [bh][d][t], 4 consecutive t -> one u64 store
          int bb2 = mb >> 11, tt = mb & 2047;
          union { unsigned short h4[4]; unsigned long long ll; } pk;
          #pragma unroll
          for (int r = 0; r < 4; ++r) pk.h4[r] = f2bf(acc[i4][nf][r] + bv);
          unsigned short* vbase = qb + 2 * SZ;
          *reinterpret_cast<unsigned long long*>(
              &vbase[((size_t)(bb2*H_ + h)*D_ + d)*T_ + tt]) = pk.ll;
        } else {
          unsigned short* base = qb + (size_t)which * SZ;
          #pragma unroll
          for (int r = 0; r < 4; ++r) {
            int m = mb + r;
            int bb2 = m >> 11, tt = m & 2047;
            float y = acc[i4][nf][r] + bv;
            if (which == 0) y *= QSCALE;
            base[((size_t)(bb2*H_ + h)*T_ + tt)*D_ + d] = f2bf(y);
          }
        }
      }
    }
  } else {
    float* out = (float*)outp;
    #pragma unroll
    for (int i4 = 0; i4 < 4; ++i4) {
      int mb = m0 + wm*64 + i4*16 + lg*4;
      #pragma unroll
      for (int nf = 0; nf < 4; ++nf) {
        int n = n0 + wn*64 + nf*16 + lr;
        float bv = bias[n];
        #pragma unroll
        for (int r = 0; r < 4; ++r)
          out[(size_t)(mb + r)*N + n] = acc[i4][nf][r] + bv;
      }
    }
  }
}

// ---------------- flash attention, 4-wave blocks, KVB=128 (round-22, verified) -----
__global__ __launch_bounds__(256, 2) void k_attn4(const unsigned short* __restrict__ Qb,
                                                  const unsigned short* __restrict__ Kb,
                                                  const unsigned short* __restrict__ Vb,
                                                  const int* __restrict__ amask,
                                                  unsigned short* __restrict__ Yb) {
  __shared__ __align__(16) char pool[65536];   // [buf][K 16KB | V^T 16KB]

  const int l = blockIdx.y * 16 + blockIdx.x;
  const int local = l >> 3;                     // 0..127
  const int tq = 15 - (local >> 3);             // q-tile index (heavy first)
  const int bh = (l & 7) * 8 + (local & 7);
  const int bb = bh >> 4, hh = bh & 15;

  const int tid = threadIdx.x;
  const int lane = tid & 63, w = tid >> 6;
  const int hi = lane >> 5, l31 = lane & 31;

  const unsigned short* Qh = Qb + (size_t)bh * (T_*D_);
  const unsigned short* Kh = Kb + (size_t)bh * (T_*D_);
  const unsigned short* Vh = Vb + (size_t)bh * (T_*D_);   // [d][t] layout

  auto stage_load = [&](int i, int b, int& nm0, int& nm1) {
    const int kv0 = i << 7;
    char* base = pool + b * 32768;
    // K tile [128 kv][64 d], granule swizzle g ^ (row&7), pre-swizzled source
    #pragma unroll
    for (int s = 0; s < 4; ++s) {
      int gi = tid + s * 256;
      int row = gi >> 3, gc = gi & 7;
      gload_lds16(Kh + (size_t)(kv0 + row)*D_ + (gc ^ (row & 7)) * 8, base + gi * 16);
    }
    // V^T tile [64 d][128 t], granule swizzle q ^ (d&15), pre-swizzled source
    #pragma unroll
    for (int s = 0; s < 4; ++s) {
      int gi = tid + s * 256;
      int d = gi >> 4, q = gi & 15;
      gload_lds16(Vh + (size_t)d*T_ + kv0 + ((q ^ (d & 15)) * 8),
                  base + 16384 + gi * 16);
    }
    nm0 = amask[bb*T_ + kv0 + lane];
    nm1 = amask[bb*T_ + kv0 + 64 + lane];
  };

  const int nT = tq + 1;                       // 128-kv tiles for this q-tile
  const int qbase = tq << 7;
  const int qw = qbase + w * 32;
  const int q  = qw + l31;

  short8 qf[4];
  #pragma unroll
  for (int dt = 0; dt < 4; ++dt)
    qf[dt] = *reinterpret_cast<const short8*>(Qh + (size_t)q*D_ + dt*16 + hi*8);

  f32x16 o0, o1;
  #pragma unroll
  for (int r = 0; r < 16; ++r) { o0[r] = 0.f; o1[r] = 0.f; }
  float mr = 0.f, ls = 0.f;                    // max-free: mr is a rescale offset

  int cm0, cm1;
  stage_load(0, 0, cm0, cm1);
  __syncthreads();

  for (int i = 0; i < nT; ++i) {
    const int b = i & 1;
    const bool pf = (i + 1 < nT);
    int nm0 = 0, nm1 = 0;
    if (pf) stage_load(i + 1, b ^ 1, nm0, nm1);   // EARLY: issue all loads
    const int kv0 = i << 7;

    const unsigned short* Klb = (const unsigned short*)(pool + b * 32768);
    const char* Vtb = pool + b * 32768 + 16384;

    // ---- S^T: 4 tiles of 32 kv x 32 q ----
    f32x16 st[4];
    #pragma unroll
    for (int tl = 0; tl < 4; ++tl)
      #pragma unroll
      for (int r = 0; r < 16; ++r) st[tl][r] = 0.f;
    __builtin_amdgcn_s_setprio(1);
    #pragma unroll
    for (int dt = 0; dt < 4; ++dt) {
      int gg = dt * 2 + hi;
      #pragma unroll
      for (int tl = 0; tl < 4; ++tl) {
        int ra = tl*32 + l31;
        short8 kf = *reinterpret_cast<const short8*>(Klb + ra*64 + ((gg ^ (ra & 7)) * 8));
        st[tl] = __builtin_amdgcn_mfma_f32_32x32x16_bf16(kf, qf[dt], st[tl], 0, 0, 0);
      }
    }
    __builtin_amdgcn_s_setprio(0);

    // causal mask (diagonal iteration only)
    if (kv0 + 127 > qw) {
      #pragma unroll
      for (int tl = 0; tl < 4; ++tl)
        #pragma unroll
        for (int r = 0; r < 16; ++r) {
          int kvl = tl*32 + (r & 3) + 8 * (r >> 2) + 4 * hi;
          if (kv0 + kvl > q) st[tl][r] = -1e30f;
        }
    }
    // pad mask (all-ones fast path)
    unsigned long long mb0 = __ballot(cm0 != 0);
    unsigned long long mb1 = __ballot(cm1 != 0);
    if ((mb0 & mb1) != ~0ull) {
      #pragma unroll
      for (int tl = 0; tl < 4; ++tl) {
        unsigned long long mb = (tl < 2) ? mb0 : mb1;
        int sh0 = (tl & 1) * 32;
        #pragma unroll
        for (int r = 0; r < 16; ++r) {
          int kvl = (r & 3) + 8 * (r >> 2) + 4 * hi;
          if (!((mb >> (kvl + sh0)) & 1)) st[tl][r] = -1e30f;
        }
      }
    }

    // ---- max-free exp2 + tree-reduced sum ----
    float rp[8];
    #pragma unroll
    for (int r = 0; r < 8; ++r) rp[r] = 0.f;
    #pragma unroll
    for (int tl = 0; tl < 4; ++tl)
      #pragma unroll
      for (int r = 0; r < 16; ++r) {
        st[tl][r] = EXP2(st[tl][r] - mr);
        rp[r & 7] += st[tl][r];
      }
    float rs = ((rp[0] + rp[1]) + (rp[2] + rp[3])) + ((rp[4] + rp[5]) + (rp[6] + rp[7]));
    rs += __shfl_xor(rs, 32);

    // ---- pack P to bf16 pair-words ----
    unsigned int pw[4][4][2];
    #pragma unroll
    for (int tl = 0; tl < 4; ++tl)
      #pragma unroll
      for (int a = 0; a < 4; ++a) {
        pw[tl][a][0] = cvtpk_bf16(st[tl][4*a],   st[tl][4*a+1]);
        pw[tl][a][1] = cvtpk_bf16(st[tl][4*a+2], st[tl][4*a+3]);
      }

    // ---- O^T += V^T x P^T over 8 k-slices of 16 kv (permlane32_swap B-frag) ----
    #pragma unroll
    for (int kt = 0; kt < 8; ++kt) {
      const int t = kt >> 1, h2 = kt & 1;
      unsigned int x0 = pw[t][2*h2][0],   x1 = pw[t][2*h2][1];
      unsigned int y0 = pw[t][2*h2+1][0], y1 = pw[t][2*h2+1][1];
      asm("v_permlane32_swap_b32 %0, %1" : "+v"(x0), "+v"(y0));
      asm("v_permlane32_swap_b32 %0, %1" : "+v"(x1), "+v"(y1));
      union { unsigned int u[4]; short8 v; } pf2;
      pf2.u[0] = x0;
      pf2.u[1] = x1;
      pf2.u[2] = y0;
      pf2.u[3] = y1;
      int gg = kt * 2 + hi;                    // 0..15
      int dA = l31;
      short8 vf0 = *reinterpret_cast<const short8*>(Vtb + dA*256 + ((gg ^ (dA & 15)) * 16));
      int dB = 32 + l31;
      short8 vf1 = *reinterpret_cast<const short8*>(Vtb + dB*256 + ((gg ^ (dB & 15)) * 16));
      __builtin_amdgcn_s_setprio(1);
      o0 = __builtin_amdgcn_mfma_f32_32x32x16_bf16(vf0, pf2.v, o0, 0, 0, 0);
      o1 = __builtin_amdgcn_mfma_f32_32x32x16_bf16(vf1, pf2.v, o1, 0, 0, 0);
      __builtin_amdgcn_s_setprio(0);
    }

    // ---- ls update + rare exact power-of-2 rescale ----
    if (__all(rs <= 65536.f)) {
      ls += rs;
    } else {
      float lgf;
      asm("v_log_f32 %0, %1" : "=v"(lgf) : "v"(rs));
      int lgi = (int)lgf + 1;                            // ceil(log2(rs))
      float corr = __int_as_float((unsigned)(127 - lgi) << 23);   // exact 2^-lgi
      mr += (float)lgi;
      ls = (ls + rs) * corr;
      #pragma unroll
      for (int r = 0; r < 16; ++r) { o0[r] *= corr; o1[r] *= corr; }
    }

    if (pf) { cm0 = nm0; cm1 = nm1; }
    __syncthreads();                           // drains K+V gloads for i+1
  }

  // ---- epilogue: direct write ----
  float inv = 1.0f / ls;
  size_t rowbase = ((size_t)bb*T_ + q)*C_ + hh*D_;
  #pragma unroll
  for (int a = 0; a < 4; ++a) {
    union { unsigned short h[4]; unsigned long long ll; } y0, y1;
    #pragma unroll
    for (int bq = 0; bq < 4; ++bq) {
      int r = 4*a + bq;
      y0.h[bq] = f2bf(o0[r] * inv);
      y1.h[bq] = f2bf(o1[r] * inv);
    }
    int d0o = 8*a + 4*hi;
    *reinterpret_cast<unsigned long long*>(Yb + rowbase + d0o)      = y0.ll;
    *reinterpret_cast<unsigned long long*>(Yb + rowbase + 32 + d0o) = y1.ll;
  }
}

extern "C" void kernel_launch(void* const* d_in, const int* in_sizes, int n_in,
                              void* d_out, int out_size, void* d_ws, size_t ws_size,
                              hipStream_t stream) {
  const float* x      = (const float*)d_in[0];
  const float* W_attn = (const float*)d_in[1];
  const float* b_attn = (const float*)d_in[2];
  const float* W_proj = (const float*)d_in[3];
  const float* b_proj = (const float*)d_in[4];
  const int*   amask  = (const int*)d_in[5];
  float* out = (float*)d_out;

  char* ws = (char*)d_ws;
  size_t off = 0;
  auto alloc = [&](size_t bytes) { char* p = ws + off; off += (bytes + 255) & ~(size_t)255; return p; };
  unsigned short* xb   = (unsigned short*)alloc((size_t)M_ * C_ * 2);
  unsigned short* Wta  = (unsigned short*)alloc((size_t)3 * C_ * C_ * 2);
  unsigned short* Wtp  = (unsigned short*)alloc((size_t)C_ * C_ * 2);
  unsigned short* qkvb = (unsigned short*)alloc((size_t)3 * BH_ * T_ * D_ * 2);
  unsigned short* Yb   = (unsigned short*)alloc((size_t)M_ * C_ * 2);

  k_cvt<<<(M_ * C_) / 1024, 256, 0, stream>>>(x, xb, M_ * C_);
  k_tr<<<dim3(3*C_/32, C_/32), dim3(32, 8), 0, stream>>>(W_attn, Wta, C_, 3*C_);
  k_tr<<<dim3(C_/32,  C_/32),  dim3(32, 8), 0, stream>>>(W_proj, Wtp, C_, C_);

  k_gemm4<1><<<dim3(3*C_/128, M_/128), 256, 0, stream>>>(xb, Wta, b_attn, qkvb, 3*C_, C_);

  unsigned short* Qb = qkvb;
  unsigned short* Kb = qkvb + (size_t)BH_ * T_ * D_;
  unsigned short* Vb = qkvb + 2 * (size_t)BH_ * T_ * D_;   // [bh][d][t]
  k_attn4<<<dim3(16, BH_), 256, 0, stream>>>(Qb, Kb, Vb, amask, Yb);

  k_gemm4<0><<<dim3(C_/128, M_/128), 256, 0, stream>>>(Yb, Wtp, b_proj, out, C_, C_);
}

// Round 25
// 153.620 us; speedup vs baseline: 1.0112x; 1.0112x over previous
//
#include <hip/hip_runtime.h>
#include <hip/hip_bf16.h>
#include <stdint.h>

#define B_ 4
#define T_ 2048
#define C_ 1024
#define H_ 16
#define D_ 64
#define BH_ (B_*H_)
#define M_ (B_*T_)   // 8192 rows

typedef __attribute__((ext_vector_type(8))) short short8;
typedef __attribute__((ext_vector_type(4))) float f32x4;
typedef __attribute__((ext_vector_type(16))) float f32x16;

#if __has_builtin(__builtin_amdgcn_exp2f)
#define EXP2(x) __builtin_amdgcn_exp2f(x)
#else
#define EXP2(x) exp2f(x)
#endif

// 1/sqrt(D) * log2(e), folded into Q at QKV-GEMM epilogue
#define QSCALE 0.18033688011112043f

__device__ __forceinline__ unsigned short f2bf(float f) {
  union { float f; unsigned int u; } v; v.f = f;
  unsigned int r = v.u + 0x7FFFu + ((v.u >> 16) & 1u);   // RNE
  return (unsigned short)(r >> 16);
}

__device__ __forceinline__ unsigned int cvtpk_bf16(float lo, float hi) {
  unsigned int r;
  asm("v_cvt_pk_bf16_f32 %0, %1, %2" : "=v"(r) : "v"(lo), "v"(hi));
  return r;
}

__device__ __forceinline__ void gload_lds16(const void* g, void* l) {
  __builtin_amdgcn_global_load_lds(
      (__attribute__((address_space(1))) void*)g,
      (__attribute__((address_space(3))) void*)l, 16, 0, 0);
}

// ---------------- fp32 -> bf16 convert (vectorized) ----------------
__global__ __launch_bounds__(256) void k_cvt(const float* __restrict__ in,
                                             unsigned short* __restrict__ out, int n) {
  int i = (blockIdx.x * 256 + threadIdx.x) * 4;
  if (i >= n) return;
  float4 v = *reinterpret_cast<const float4*>(in + i);
  union { unsigned short u[4]; unsigned long long ll; } o;
  o.u[0] = f2bf(v.x); o.u[1] = f2bf(v.y); o.u[2] = f2bf(v.z); o.u[3] = f2bf(v.w);
  *reinterpret_cast<unsigned long long*>(out + i) = o.ll;
}

// ---------------- transpose+convert W [K][N] f32 -> Wt [N][K] bf16 ----------------
__global__ __launch_bounds__(256) void k_tr(const float* __restrict__ W,
                                            unsigned short* __restrict__ Wt, int K, int N) {
  __shared__ float t[32][33];
  int n0 = blockIdx.x * 32, k0 = blockIdx.y * 32;
  int tx = threadIdx.x, ty = threadIdx.y;    // (32,8)
  #pragma unroll
  for (int j = 0; j < 4; j++)
    t[ty + j*8][tx] = W[(size_t)(k0 + ty + j*8) * N + n0 + tx];
  __syncthreads();
  #pragma unroll
  for (int j = 0; j < 4; j++)
    Wt[(size_t)(n0 + ty + j*8) * K + k0 + tx] = f2bf(t[tx][ty + j*8]);
}

// ---------------- GEMM v4.1: 128x128, BK=64, 4 waves, 64KB LDS, 2 blocks/CU --------
// SINGLE-BARRIER K-tile (round-23, verified best): one {read all frags | stage both
// | lgkm0 | 32 MFMA | vmcnt(0) | s_barrier} per K-tile.
template<int QKV>
__global__ __launch_bounds__(256) void k_gemm4(const unsigned short* __restrict__ A,
                                               const unsigned short* __restrict__ Bt,
                                               const float* __restrict__ bias,
                                               void* __restrict__ outp, int N, int K) {
  __shared__ __align__(16) unsigned short Al[2][128*64];   // 32 KB
  __shared__ __align__(16) unsigned short Bl[2][128*64];   // 32 KB

  const int tid = threadIdx.x;
  const int lane = tid & 63, wv = tid >> 6;
  const int lg = lane >> 4, lr = lane & 15;
  const int wm = wv >> 1, wn = wv & 1;     // 2M x 2N

  // T1: XCD-aware chunked remap (nwg % 8 == 0: 1536 / 512)
  const int nwg = gridDim.x * gridDim.y;
  const int l = blockIdx.y * gridDim.x + blockIdx.x;
  const int wg = (l & 7) * (nwg >> 3) + (l >> 3);
  const int m0 = (wg / gridDim.x) * 128;
  const int n0 = (wg % gridDim.x) * 128;

  const int NT = K >> 6;

  auto stageA = [&](int s, int t) {
    #pragma unroll
    for (int u = 0; u < 4; ++u) {
      int gi = tid + u*256;
      int row = gi >> 3, g = gi & 7;
      gload_lds16(A + (size_t)(m0 + row) * K + t*64 + (g ^ (row & 7)) * 8,
                  (char*)Al[s] + gi*16);
    }
  };
  auto stageB = [&](int s, int t) {
    #pragma unroll
    for (int u = 0; u < 4; ++u) {
      int gi = tid + u*256;
      int row = gi >> 3, g = gi & 7;
      gload_lds16(Bt + (size_t)(n0 + row) * K + t*64 + (g ^ (row & 7)) * 8,
                  (char*)Bl[s] + gi*16);
    }
  };

  f32x4 acc[4][4];
  #pragma unroll
  for (int i = 0; i < 4; ++i)
    #pragma unroll
    for (int j = 0; j < 4; ++j) acc[i][j] = (f32x4){0.f, 0.f, 0.f, 0.f};

  stageA(0, 0); stageB(0, 0);
  asm volatile("s_waitcnt vmcnt(0)" ::: "memory");
  __builtin_amdgcn_s_barrier();

  for (int t = 0; t < NT; ++t) {
    const char* Asb = (const char*)Al[t & 1];
    const char* Bsb = (const char*)Bl[t & 1];
    const int s1 = (t & 1) ^ 1;
    const bool sn = (t + 1 < NT);
    short8 af[4][2], bf[4][2];

    // read all A + B fragments of tile t (16 x ds_read_b128, swizzled)
    #pragma unroll
    for (int mf = 0; mf < 4; ++mf) {
      int row = wm*64 + mf*16 + lr; int r7 = row & 7;
      af[mf][0] = *(const short8*)(Asb + row*128 + ((lg      ^ r7) << 4));
      af[mf][1] = *(const short8*)(Asb + row*128 + (((4|lg) ^ r7) << 4));
    }
    #pragma unroll
    for (int nf = 0; nf < 4; ++nf) {
      int col = wn*64 + nf*16 + lr; int c7 = col & 7;
      bf[nf][0] = *(const short8*)(Bsb + col*128 + ((lg      ^ c7) << 4));
      bf[nf][1] = *(const short8*)(Bsb + col*128 + (((4|lg) ^ c7) << 4));
    }
    // stage tile t+1 into the other buffer (8 gloads, full-tile flight)
    if (sn) { stageA(s1, t + 1); stageB(s1, t + 1); }

    asm volatile("s_waitcnt lgkmcnt(0)" ::: "memory");
    __builtin_amdgcn_sched_barrier(0);
    __builtin_amdgcn_s_setprio(1);
    #pragma unroll
    for (int kh = 0; kh < 2; ++kh)
      #pragma unroll
      for (int mf = 0; mf < 4; ++mf)
        #pragma unroll
        for (int nf = 0; nf < 4; ++nf)
          acc[mf][nf] = __builtin_amdgcn_mfma_f32_16x16x32_bf16(
              af[mf][kh], bf[nf][kh], acc[mf][nf], 0, 0, 0);
    __builtin_amdgcn_s_setprio(0);

    asm volatile("s_waitcnt vmcnt(0)" ::: "memory");
    __builtin_amdgcn_s_barrier();
  }

  if (QKV) {
    unsigned short* qb = (unsigned short*)outp;
    const size_t SZ = (size_t)BH_ * T_ * D_;
    #pragma unroll
    for (int i4 = 0; i4 < 4; ++i4) {
      int mb = m0 + wm*64 + i4*16 + lg*4;
      #pragma unroll
      for (int nf = 0; nf < 4; ++nf) {
        int n = n0 + wn*64 + nf*16 + lr;
        float bv = bias[n];
        int which = n >> 10, c = n & 1023, h = c >> 6, d = c & 63;
        if (which == 2) {
          // V: transposed [bh][d][t], 4 consecutive t -> one u64 store
          int bb2 = mb >> 11, tt = mb & 2047;
          union { unsigned short h4[4]; unsigned long long ll; } pk;
          #pragma unroll
          for (int r = 0; r < 4; ++r) pk.h4[r] = f2bf(acc[i4][nf][r] + bv);
          unsigned short* vbase = qb + 2 * SZ;
          *reinterpret_cast<unsigned long long*>(
              &vbase[((size_t)(bb2*H_ + h)*D_ + d)*T_ + tt]) = pk.ll;
        } else {
          unsigned short* base = qb + (size_t)which * SZ;
          #pragma unroll
          for (int r = 0; r < 4; ++r) {
            int m = mb + r;
            int bb2 = m >> 11, tt = m & 2047;
            float y = acc[i4][nf][r] + bv;
            if (which == 0) y *= QSCALE;
            base[((size_t)(bb2*H_ + h)*T_ + tt)*D_ + d] = f2bf(y);
          }
        }
      }
    }
  } else {
    float* out = (float*)outp;
    #pragma unroll
    for (int i4 = 0; i4 < 4; ++i4) {
      int mb = m0 + wm*64 + i4*16 + lg*4;
      #pragma unroll
      for (int nf = 0; nf < 4; ++nf) {
        int n = n0 + wn*64 + nf*16 + lr;
        float bv = bias[n];
        #pragma unroll
        for (int r = 0; r < 4; ++r)
          out[(size_t)(mb + r)*N + n] = acc[i4][nf][r] + bv;
      }
    }
  }
}

// ---------------- flash attention, 4-wave blocks, KVB=128 (round-22, verified) -----
__global__ __launch_bounds__(256, 2) void k_attn4(const unsigned short* __restrict__ Qb,
                                                  const unsigned short* __restrict__ Kb,
                                                  const unsigned short* __restrict__ Vb,
                                                  const int* __restrict__ amask,
                                                  unsigned short* __restrict__ Yb) {
  __shared__ __align__(16) char pool[65536];   // [buf][K 16KB | V^T 16KB]

  const int l = blockIdx.y * 16 + blockIdx.x;
  const int local = l >> 3;                     // 0..127
  const int tq = 15 - (local >> 3);             // q-tile index (heavy first)
  const int bh = (l & 7) * 8 + (local & 7);
  const int bb = bh >> 4, hh = bh & 15;

  const int tid = threadIdx.x;
  const int lane = tid & 63, w = tid >> 6;
  const int hi = lane >> 5, l31 = lane & 31;

  const unsigned short* Qh = Qb + (size_t)bh * (T_*D_);
  const unsigned short* Kh = Kb + (size_t)bh * (T_*D_);
  const unsigned short* Vh = Vb + (size_t)bh * (T_*D_);   // [d][t] layout

  auto stage_load = [&](int i, int b, int& nm0, int& nm1) {
    const int kv0 = i << 7;
    char* base = pool + b * 32768;
    // K tile [128 kv][64 d], granule swizzle g ^ (row&7), pre-swizzled source
    #pragma unroll
    for (int s = 0; s < 4; ++s) {
      int gi = tid + s * 256;
      int row = gi >> 3, gc = gi & 7;
      gload_lds16(Kh + (size_t)(kv0 + row)*D_ + (gc ^ (row & 7)) * 8, base + gi * 16);
    }
    // V^T tile [64 d][128 t], granule swizzle q ^ (d&15), pre-swizzled source
    #pragma unroll
    for (int s = 0; s < 4; ++s) {
      int gi = tid + s * 256;
      int d = gi >> 4, q = gi & 15;
      gload_lds16(Vh + (size_t)d*T_ + kv0 + ((q ^ (d & 15)) * 8),
                  base + 16384 + gi * 16);
    }
    nm0 = amask[bb*T_ + kv0 + lane];
    nm1 = amask[bb*T_ + kv0 + 64 + lane];
  };

  const int nT = tq + 1;                       // 128-kv tiles for this q-tile
  const int qbase = tq << 7;
  const int qw = qbase + w * 32;
  const int q  = qw + l31;

  short8 qf[4];
  #pragma unroll
  for (int dt = 0; dt < 4; ++dt)
    qf[dt] = *reinterpret_cast<const short8*>(Qh + (size_t)q*D_ + dt*16 + hi*8);

  f32x16 o0, o1;
  #pragma unroll
  for (int r = 0; r < 16; ++r) { o0[r] = 0.f; o1[r] = 0.f; }
  float mr = 0.f, ls = 0.f;                    // max-free: mr is a rescale offset

  int cm0, cm1;
  stage_load(0, 0, cm0, cm1);
  __syncthreads();

  for (int i = 0; i < nT; ++i) {
    const int b = i & 1;
    const bool pf = (i + 1 < nT);
    int nm0 = 0, nm1 = 0;
    if (pf) stage_load(i + 1, b ^ 1, nm0, nm1);   // EARLY: issue all loads
    const int kv0 = i << 7;

    const unsigned short* Klb = (const unsigned short*)(pool + b * 32768);
    const char* Vtb = pool + b * 32768 + 16384;

    // ---- S^T: 4 tiles of 32 kv x 32 q ----
    f32x16 st[4];
    #pragma unroll
    for (int tl = 0; tl < 4; ++tl)
      #pragma unroll
      for (int r = 0; r < 16; ++r) st[tl][r] = 0.f;
    __builtin_amdgcn_s_setprio(1);
    #pragma unroll
    for (int dt = 0; dt < 4; ++dt) {
      int gg = dt * 2 + hi;
      #pragma unroll
      for (int tl = 0; tl < 4; ++tl) {
        int ra = tl*32 + l31;
        short8 kf = *reinterpret_cast<const short8*>(Klb + ra*64 + ((gg ^ (ra & 7)) * 8));
        st[tl] = __builtin_amdgcn_mfma_f32_32x32x16_bf16(kf, qf[dt], st[tl], 0, 0, 0);
      }
    }
    __builtin_amdgcn_s_setprio(0);

    // causal mask (diagonal iteration only)
    if (kv0 + 127 > qw) {
      #pragma unroll
      for (int tl = 0; tl < 4; ++tl)
        #pragma unroll
        for (int r = 0; r < 16; ++r) {
          int kvl = tl*32 + (r & 3) + 8 * (r >> 2) + 4 * hi;
          if (kv0 + kvl > q) st[tl][r] = -1e30f;
        }
    }
    // pad mask (all-ones fast path)
    unsigned long long mb0 = __ballot(cm0 != 0);
    unsigned long long mb1 = __ballot(cm1 != 0);
    if ((mb0 & mb1) != ~0ull) {
      #pragma unroll
      for (int tl = 0; tl < 4; ++tl) {
        unsigned long long mb = (tl < 2) ? mb0 : mb1;
        int sh0 = (tl & 1) * 32;
        #pragma unroll
        for (int r = 0; r < 16; ++r) {
          int kvl = (r & 3) + 8 * (r >> 2) + 4 * hi;
          if (!((mb >> (kvl + sh0)) & 1)) st[tl][r] = -1e30f;
        }
      }
    }

    // ---- max-free exp2 + tree-reduced sum ----
    float rp[8];
    #pragma unroll
    for (int r = 0; r < 8; ++r) rp[r] = 0.f;
    #pragma unroll
    for (int tl = 0; tl < 4; ++tl)
      #pragma unroll
      for (int r = 0; r < 16; ++r) {
        st[tl][r] = EXP2(st[tl][r] - mr);
        rp[r & 7] += st[tl][r];
      }
    float rs = ((rp[0] + rp[1]) + (rp[2] + rp[3])) + ((rp[4] + rp[5]) + (rp[6] + rp[7]));
    rs += __shfl_xor(rs, 32);

    // ---- pack P to bf16 pair-words ----
    unsigned int pw[4][4][2];
    #pragma unroll
    for (int tl = 0; tl < 4; ++tl)
      #pragma unroll
      for (int a = 0; a < 4; ++a) {
        pw[tl][a][0] = cvtpk_bf16(st[tl][4*a],   st[tl][4*a+1]);
        pw[tl][a][1] = cvtpk_bf16(st[tl][4*a+2], st[tl][4*a+3]);
      }

    // ---- O^T += V^T x P^T over 8 k-slices of 16 kv (permlane32_swap B-frag) ----
    #pragma unroll
    for (int kt = 0; kt < 8; ++kt) {
      const int t = kt >> 1, h2 = kt & 1;
      unsigned int x0 = pw[t][2*h2][0],   x1 = pw[t][2*h2][1];
      unsigned int y0 = pw[t][2*h2+1][0], y1 = pw[t][2*h2+1][1];
      asm("v_permlane32_swap_b32 %0, %1" : "+v"(x0), "+v"(y0));
      asm("v_permlane32_swap_b32 %0, %1" : "+v"(x1), "+v"(y1));
      union { unsigned int u[4]; short8 v; } pf2;
      pf2.u[0] = x0;
      pf2.u[1] = x1;
      pf2.u[2] = y0;
      pf2.u[3] = y1;
      int gg = kt * 2 + hi;                    // 0..15
      int dA = l31;
      short8 vf0 = *reinterpret_cast<const short8*>(Vtb + dA*256 + ((gg ^ (dA & 15)) * 16));
      int dB = 32 + l31;
      short8 vf1 = *reinterpret_cast<const short8*>(Vtb + dB*256 + ((gg ^ (dB & 15)) * 16));
      __builtin_amdgcn_s_setprio(1);
      o0 = __builtin_amdgcn_mfma_f32_32x32x16_bf16(vf0, pf2.v, o0, 0, 0, 0);
      o1 = __builtin_amdgcn_mfma_f32_32x32x16_bf16(vf1, pf2.v, o1, 0, 0, 0);
      __builtin_amdgcn_s_setprio(0);
    }

    // ---- ls update + rare exact power-of-2 rescale ----
    if (__all(rs <= 65536.f)) {
      ls += rs;
    } else {
      float lgf;
      asm("v_log_f32 %0, %1" : "=v"(lgf) : "v"(rs));
      int lgi = (int)lgf + 1;                            // ceil(log2(rs))
      float corr = __int_as_float((unsigned)(127 - lgi) << 23);   // exact 2^-lgi
      mr += (float)lgi;
      ls = (ls + rs) * corr;
      #pragma unroll
      for (int r = 0; r < 16; ++r) { o0[r] *= corr; o1[r] *= corr; }
    }

    if (pf) { cm0 = nm0; cm1 = nm1; }
    __syncthreads();                           // drains K+V gloads for i+1
  }

  // ---- epilogue: direct write ----
  float inv = 1.0f / ls;
  size_t rowbase = ((size_t)bb*T_ + q)*C_ + hh*D_;
  #pragma unroll
  for (int a = 0; a < 4; ++a) {
    union { unsigned short h[4]; unsigned long long ll; } y0, y1;
    #pragma unroll
    for (int bq = 0; bq < 4; ++bq) {
      int r = 4*a + bq;
      y0.h[bq] = f2bf(o0[r] * inv);
      y1.h[bq] = f2bf(o1[r] * inv);
    }
    int d0o = 8*a + 4*hi;
    *reinterpret_cast<unsigned long long*>(Yb + rowbase + d0o)      = y0.ll;
    *reinterpret_cast<unsigned long long*>(Yb + rowbase + 32 + d0o) = y1.ll;
  }
}

extern "C" void kernel_launch(void* const* d_in, const int* in_sizes, int n_in,
                              void* d_out, int out_size, void* d_ws, size_t ws_size,
                              hipStream_t stream) {
  const float* x      = (const float*)d_in[0];
  const float* W_attn = (const float*)d_in[1];
  const float* b_attn = (const float*)d_in[2];
  const float* W_proj = (const float*)d_in[3];
  const float* b_proj = (const float*)d_in[4];
  const int*   amask  = (const int*)d_in[5];
  float* out = (float*)d_out;

  char* ws = (char*)d_ws;
  size_t off = 0;
  auto alloc = [&](size_t bytes) { char* p = ws + off; off += (bytes + 255) & ~(size_t)255; return p; };
  unsigned short* xb   = (unsigned short*)alloc((size_t)M_ * C_ * 2);
  unsigned short* Wta  = (unsigned short*)alloc((size_t)3 * C_ * C_ * 2);
  unsigned short* Wtp  = (unsigned short*)alloc((size_t)C_ * C_ * 2);
  unsigned short* qkvb = (unsigned short*)alloc((size_t)3 * BH_ * T_ * D_ * 2);
  unsigned short* Yb   = (unsigned short*)alloc((size_t)M_ * C_ * 2);

  k_cvt<<<(M_ * C_) / 1024, 256, 0, stream>>>(x, xb, M_ * C_);
  k_tr<<<dim3(3*C_/32, C_/32), dim3(32, 8), 0, stream>>>(W_attn, Wta, C_, 3*C_);
  k_tr<<<dim3(C_/32,  C_/32),  dim3(32, 8), 0, stream>>>(W_proj, Wtp, C_, C_);

  k_gemm4<1><<<dim3(3*C_/128, M_/128), 256, 0, stream>>>(xb, Wta, b_attn, qkvb, 3*C_, C_);

  unsigned short* Qb = qkvb;
  unsigned short* Kb = qkvb + (size_t)BH_ * T_ * D_;
  unsigned short* Vb = qkvb + 2 * (size_t)BH_ * T_ * D_;   // [bh][d][t]
  k_attn4<<<dim3(16, BH_), 256, 0, stream>>>(Qb, Kb, Vb, amask, Yb);

  k_gemm4<0><<<dim3(C_/128, M_/128), 256, 0, stream>>>(Yb, Wtp, b_proj, out, C_, C_);
}